// Round 12
// baseline (243.289 us; speedup 1.0000x reference)
//
#include <hip/hip_runtime.h>
#include <math.h>

#define NXD 320
#define NYD 320
#define NCD 12
#define NTD 16
#define NPIX (NXD*NYD)   // 102400

#define PI_F 3.14159265358979323846f

// ---------------- per-lane twiddle cache ----------------
struct Tw {
    float c[6], s[6], sg[6];  // stage twiddles (identity on lower lanes) + butterfly sign
    float rc[4], rs[4];       // w320^(n*k2), n=1..4
    int   k2;                 // bitrev6(lane)
};

__device__ __forceinline__ void make_tw(Tw& tw, int lane) {
#pragma unroll
    for (int i = 0; i < 6; i++) {
        int h = 32 >> i;
        float ang = -2.0f * PI_F * (float)(lane & (h - 1)) / (float)(2 * h);
        float s, c;
        sincosf(ang, &s, &c);
        bool hi = (lane & h) != 0;
        tw.c[i]  = hi ? c : 1.0f;
        tw.s[i]  = hi ? s : 0.0f;
        tw.sg[i] = hi ? -1.0f : 1.0f;
    }
    tw.k2 = (int)(__brev((unsigned)lane) >> 26);   // 6-bit reversal
#pragma unroll
    for (int n = 1; n <= 4; n++) {
        float ang = -2.0f * PI_F * (float)(n * tw.k2) / 320.0f;
        sincosf(ang, &tw.rs[n - 1], &tw.rc[n - 1]);
    }
}

// 320-pt FFT: input  zr/zi[n] = x[5*lane + n]
//             output zr/zi[j] = X[tw.k2 + 64*j]   (bit-reversed k2 order)
__device__ __forceinline__ void fft320(float zr[5], float zi[5], const Tw& tw) {
#pragma unroll
    for (int i = 0; i < 6; i++) {
        const int h = 32 >> i;
        const float wc = tw.c[i], ws = tw.s[i], sg = tw.sg[i];
#pragma unroll
        for (int n = 0; n < 5; n++) {
            float orr = __shfl_xor(zr[n], h);
            float oii = __shfl_xor(zi[n], h);
            float ar = fmaf(sg, zr[n], orr);
            float ai = fmaf(sg, zi[n], oii);
            zr[n] = fmaf(ar, wc, -(ai * ws));
            zi[n] = fmaf(ar, ws,   ai * wc);
        }
    }
    float ar[5], ai[5];
    ar[0] = zr[0]; ai[0] = zi[0];
#pragma unroll
    for (int n = 1; n < 5; n++) {
        ar[n] = zr[n] * tw.rc[n - 1] - zi[n] * tw.rs[n - 1];
        ai[n] = zr[n] * tw.rs[n - 1] + zi[n] * tw.rc[n - 1];
    }
    const float w5c[5] = { 1.0f,  0.30901699437494742f, -0.80901699437494745f,
                           -0.80901699437494745f,  0.30901699437494742f };
    const float w5s[5] = { 0.0f, -0.95105651629515357f, -0.58778525229247312f,
                            0.58778525229247312f,  0.95105651629515357f };
#pragma unroll
    for (int j = 0; j < 5; j++) {
        float xr = ar[0], xi = ai[0];
#pragma unroll
        for (int n = 1; n < 5; n++) {
            const int m = (j * n) % 5;
            xr += ar[n] * w5c[m] - ai[n] * w5s[m];
            xi += ar[n] * w5s[m] + ai[n] * w5c[m];
        }
        zr[j] = xr; zi[j] = xi;
    }
}

// ---------------- K0: combine image, pack mask bits ----------------
__global__ __launch_bounds__(256) void k_prep(const float* __restrict__ imr,
                                              const float* __restrict__ imi,
                                              const float* __restrict__ mask,
                                              float2* __restrict__ imc,
                                              unsigned short* __restrict__ mp) {
    int p = blockIdx.x * 256 + threadIdx.x;
    imc[p] = make_float2(imr[p], imi[p]);
    const float4* m4 = (const float4*)(mask + (size_t)p * NTD);   // 64B aligned
    unsigned int m = 0;
#pragma unroll
    for (int q = 0; q < 4; q++) {
        float4 v = m4[q];
        m |= (v.x > 0.5f ? 1u : 0u) << (4 * q + 0);
        m |= (v.y > 0.5f ? 1u : 0u) << (4 * q + 1);
        m |= (v.z > 0.5f ? 1u : 0u) << (4 * q + 2);
        m |= (v.w > 0.5f ? 1u : 0u) << (4 * q + 3);
    }
    mp[p] = (unsigned short)m;
}

// ---------------- K1: fused warp + FFT along y ----------------
// grid (320, ceil(F/4)), block 256 = 4 waves; wave w -> frame tt = by*4+w (tt<F active)
// frames [t0,t0+F), coils [c0,c0+CG); G plane = tt*CG + cc
template<int CG>
__global__ __launch_bounds__(256) void k_fft_y(const float2* __restrict__ imc,
                                               const float* __restrict__ flow,
                                               const float* __restrict__ sr,
                                               const float* __restrict__ si,
                                               float2* __restrict__ G,
                                               int t0, int F, int c0) {
    __shared__ float2 srow[CG][NYD];
    int tid = threadIdx.x, lane = tid & 63, w = tid >> 6;
    int x = blockIdx.x;
    int tt = blockIdx.y * 4 + w;
    bool active = tt < F;
    int t = active ? (t0 + tt) : t0;    // clamp: inactive waves must not read OOB
    Tw tw; make_tw(tw, lane);
    // inline bilinear warp of this row's 5 pixels
    // flow[((x*320+y)*2+comp)*16 + t] = frow[y*32 + comp*16]
    const float* frow = flow + (size_t)x * NYD * 2 * NTD + t;
    float wr[5], wi[5];
#pragma unroll
    for (int n = 0; n < 5; n++) {
        int y = 5 * lane + n;
        float f0 = frow[(size_t)y * (2 * NTD)];
        float f1 = frow[(size_t)y * (2 * NTD) + NTD];
        float fx = fminf(fmaxf((float)x + f0, 0.0f), (float)(NXD - 1));
        float fy = fminf(fmaxf((float)y + f1, 0.0f), (float)(NYD - 1));
        float xf = floorf(fx), yf = floorf(fy);
        float wx = fx - xf, wy = fy - yf;
        int x0 = (int)xf, y0 = (int)yf;
        int x1 = min(x0 + 1, NXD - 1), y1 = min(y0 + 1, NYD - 1);
        float2 v00 = imc[x0 * NYD + y0], v10 = imc[x1 * NYD + y0];
        float2 v01 = imc[x0 * NYD + y1], v11 = imc[x1 * NYD + y1];
        float w00 = (1.0f - wx) * (1.0f - wy), w10 = wx * (1.0f - wy);
        float w01 = (1.0f - wx) * wy,          w11 = wx * wy;
        float vr = w00 * v00.x + w10 * v10.x + w01 * v01.x + w11 * v11.x;
        float vi = w00 * v00.y + w10 * v10.y + w01 * v01.y + w11 * v11.y;
        float sgn = ((x + y) & 1) ? -1.0f : 1.0f;   // (-1)^(x+y) input centering
        wr[n] = sgn * vr; wi[n] = sgn * vi;
    }
    // stage CG coil rows straight from interleaved smaps (dense when CG==12)
    const float* sbr = sr + (size_t)x * (NYD * NCD) + c0;
    const float* sbi = si + (size_t)x * (NYD * NCD) + c0;
    for (int idx = tid; idx < NYD * CG; idx += 256) {
        int i = idx / CG, cc = idx - i * CG;
        srow[cc][i] = make_float2(sbr[i * NCD + cc], sbi[i * NCD + cc]);
    }
    __syncthreads();
    for (int cc = 0; cc < CG; cc++) {
        float zr[5], zi[5];
#pragma unroll
        for (int n = 0; n < 5; n++) {
            float2 s = srow[cc][5 * lane + n];   // 2-way bank alias: free
            zr[n] = wr[n] * s.x - wi[n] * s.y;
            zi[n] = wr[n] * s.y + wi[n] * s.x;
        }
        fft320(zr, zi, tw);
        // bit-reverse fix across lanes -> coalesced store
#pragma unroll
        for (int j = 0; j < 5; j++) {
            zr[j] = __shfl(zr[j], tw.k2);
            zi[j] = __shfl(zi[j], tw.k2);
        }
        if (active) {
            float2* grow = G + ((size_t)(tt * CG + cc) * NXD + x) * NYD;
#pragma unroll
            for (int j = 0; j < 5; j++)
                grow[lane + 64 * j] = make_float2(zr[j], zi[j]);
        }
    }
}

// ---------------- K2: FFT along x, mask, accumulate frames into out ----------------
// grid (CG, 40), block 512 = 8 waves; wave w handles column ky0 + w
// realOnly: d_out is float32 real-part only (harness astype(np.float32) on complex64)
template<int CG>
__global__ __launch_bounds__(512) void k_fft_x(const float2* __restrict__ G,
                                               const unsigned short* __restrict__ mp,
                                               void* __restrict__ outv,
                                               int t0, int F, int c0, int first,
                                               int realOnly) {
    __shared__ float2 tile[2][NXD][11];
    int tid = threadIdx.x, lane = tid & 63, w = tid >> 6;
    int cx = blockIdx.x;                 // coil within group
    int c = c0 + cx;
    int ky0 = blockIdx.y * 8;
    int ky = ky0 + w;
    Tw tw; make_tw(tw, lane);
    unsigned int mb[5];
#pragma unroll
    for (int j = 0; j < 5; j++)
        mb[j] = mp[(tw.k2 + 64 * j) * NYD + ky];
    float accr[5] = {0, 0, 0, 0, 0}, acci[5] = {0, 0, 0, 0, 0};
    // prologue: stage frame tt=0
    {
        const float2* g = G + (size_t)cx * NPIX;
#pragma unroll
        for (int q = 0; q < 5; q++) {
            int m = tid + 512 * q;
            int xx = m >> 3, kk = m & 7;
            tile[0][xx][kk] = g[xx * NYD + ky0 + kk];
        }
    }
    __syncthreads();
    for (int tt = 0; tt < F; tt++) {
        int cur = tt & 1;
        if (tt + 1 < F) {    // prefetch next frame; vmcnt-wait lands after the FFT
            const float2* g = G + (size_t)((tt + 1) * CG + cx) * NPIX;
#pragma unroll
            for (int q = 0; q < 5; q++) {
                int m = tid + 512 * q;
                int xx = m >> 3, kk = m & 7;
                tile[cur ^ 1][xx][kk] = g[xx * NYD + ky0 + kk];
            }
        }
        float zr[5], zi[5];
#pragma unroll
        for (int n = 0; n < 5; n++) {
            float2 v = tile[cur][5 * lane + n][w];
            zr[n] = v.x; zi[n] = v.y;
        }
        fft320(zr, zi, tw);
        int t = t0 + tt;
#pragma unroll
        for (int j = 0; j < 5; j++) {
            float bit = (float)((mb[j] >> t) & 1u);
            accr[j] = fmaf(bit, zr[j], accr[j]);
            acci[j] = fmaf(bit, zi[j], acci[j]);
        }
        __syncthreads();
    }
    // epilogue: centering sign + ortho scale; un-bit-reverse via LDS transpose;
    // write/accumulate (kx,ky,c) output — real-part float32 or interleaved complex
#pragma unroll
    for (int j = 0; j < 5; j++) {
        int kx = tw.k2 + 64 * j;
        float sc = (((kx + ky) & 1) ? -1.0f : 1.0f) * (1.0f / 320.0f);
        tile[0][kx][w] = make_float2(accr[j] * sc, acci[j] * sc);
    }
    __syncthreads();
#pragma unroll
    for (int q = 0; q < 5; q++) {
        int m = tid + 512 * q;
        int xx = m >> 3, kk = m & 7;     // xx = linear kx, kk = ky offset
        size_t base = ((size_t)xx * NYD + ky0 + kk) * NCD + c;
        float2 v = tile[0][xx][kk];
        if (realOnly) {
            float* of = (float*)outv;    // out_size = NPIX*NCD floats
            if (first) of[base] = v.x;
            else       of[base] += v.x;
        } else {
            float2* of = (float2*)outv;  // out_size >= 2*NPIX*NCD floats
            if (first) of[base] = v;
            else { float2 o = of[base]; of[base] = make_float2(o.x + v.x, o.y + v.y); }
        }
    }
}

extern "C" void kernel_launch(void* const* d_in, const int* in_sizes, int n_in,
                              void* d_out, int out_size, void* d_ws, size_t ws_size,
                              hipStream_t stream) {
    const float* imr  = (const float*)d_in[0];
    const float* imi  = (const float*)d_in[1];
    const float* mask = (const float*)d_in[2];
    const float* sr   = (const float*)d_in[3];
    const float* si   = (const float*)d_in[4];
    const float* flow = (const float*)d_in[5];

    // fixed scratch: 1,024,000 B; G chunk after
    char* ws = (char*)d_ws;
    unsigned short* mp  = (unsigned short*)(ws);          //   204,800
    float2*         imc = (float2*)(ws + 204800);         //   819,200
    float2*         G   = (float2*)(ws + 1024000);

    // out_size == NPIX*NCD (1,228,800): harness coerced complex64 -> float32 real part
    int realOnly = (out_size < 2 * NPIX * NCD) ? 1 : 0;

    // largest (frames F, coil-group CG) whose G = F*CG planes fits
    const size_t fixed = 1024000;
    const size_t plane = (size_t)NPIX * sizeof(float2);   // 819,200 B
    const int cF[10]  = {16, 8, 4, 2, 1, 1, 1, 1, 1, 1};
    const int cCG[10] = {12, 12, 12, 12, 12, 6, 4, 3, 2, 1};
    int F = 1, CG = 1;
    for (int i = 0; i < 10; i++) {
        size_t need = fixed + (size_t)cF[i] * cCG[i] * plane;
        if (need <= ws_size) { F = cF[i]; CG = cCG[i]; break; }
    }

    k_prep<<<400, 256, 0, stream>>>(imr, imi, mask, imc, mp);
    for (int c0 = 0; c0 < NCD; c0 += CG) {
        for (int t0 = 0; t0 < NTD; t0 += F) {
            int first = (t0 == 0);
            dim3 gy(320, (F + 3) / 4);
            switch (CG) {
#define LAUNCH_CASE(CGV) \
            case CGV: \
                k_fft_y<CGV><<<gy, 256, 0, stream>>>(imc, flow, sr, si, G, t0, F, c0); \
                k_fft_x<CGV><<<dim3(CGV, 40), 512, 0, stream>>>(G, mp, d_out, t0, F, c0, first, realOnly); \
                break;
            LAUNCH_CASE(12)
            LAUNCH_CASE(6)
            LAUNCH_CASE(4)
            LAUNCH_CASE(3)
            LAUNCH_CASE(2)
            LAUNCH_CASE(1)
#undef LAUNCH_CASE
            }
        }
    }
}